// Round 14
// baseline (514.056 us; speedup 1.0000x reference)
//
#include <hip/hip_runtime.h>
#include <hip/hip_bf16.h>

typedef __hip_bfloat16 bf16;
typedef __attribute__((ext_vector_type(8))) short short8v;
typedef __attribute__((ext_vector_type(4))) float f32x4;

__device__ __forceinline__ float b2f(bf16 v){ return __bfloat162float(v); }
__device__ __forceinline__ bf16 f2b(float v){ return __float2bfloat16(v); }
__device__ __forceinline__ float softplus_f(float x){ return (x > 15.f) ? x : __logf(1.f + __expf(x)); }
__device__ __forceinline__ float sigmoid_f(float x){ return 1.f / (1.f + __expf(-x)); }

// ---------------- one-shot weight -> MFMA-fragment precompute (proven) ----------------
__global__ __launch_bounds__(256) void k_prep_w(const float* __restrict__ Wfull, const float* __restrict__ Wadj,
    const float* __restrict__ Wedge, const float* __restrict__ Watom, bf16* __restrict__ prep){
  int idx = blockIdx.x*256 + threadIdx.x;
  if (idx >= 15616) return;
  bf16 tmp[8];
  if (idx < 6144){
    int l = idx >> 11, rem = idx & 2047;
    int tc = rem >> 7, h = (rem >> 6) & 1, L = rem & 63;
    int rw = tc*16 + (L & 15);
    int c = rw & 127;
    int e0 = ((rw < 128) ? 0 : 64) + h*32 + ((L >> 4)*8);
    const float* src = Wfull + (size_t)l*21632 + (size_t)c*169 + e0;
    #pragma unroll
    for (int j = 0; j < 8; j++) tmp[j] = f2b(src[j]);
  } else if (idx < 9216){
    int u = idx - 6144;
    int l = u >> 10, rem = u & 1023;
    int tc = rem >> 7, h = (rem >> 6) & 1, L = rem & 63;
    int c = tc*16 + (L & 15);
    int k0 = h*32 + ((L >> 4)*8);
    #pragma unroll
    for (int j = 0; j < 8; j++){
      int k = k0 + j;
      tmp[j] = f2b(k < 41 ? Wfull[(size_t)l*21632 + (size_t)c*169 + 128 + k] : 0.f);
    }
  } else if (idx < 14848){
    int u = idx - 9216;
    int k = u >> 9, rem = u & 511;
    int w = rem >> 7, h = (rem >> 6) & 1, L = rem & 63;
    const float* Wk = (k < 6) ? (Wadj + (size_t)k*4096) : (Wedge + (size_t)(k-6)*4096);
    int row = w*16 + (L & 15);
    int e0 = h*32 + ((L >> 4)*8);
    #pragma unroll
    for (int j = 0; j < 8; j++) tmp[j] = f2b(Wk[(size_t)row*64 + e0 + j]);
  } else {
    int u = idx - 14848;
    int oc = u >> 7, dc = (u >> 6) & 1, L = u & 63;
    int o = oc*16 + (L & 15);
    int dbase = ((L >> 4)*8) + dc*32;
    #pragma unroll
    for (int j = 0; j < 8; j++) tmp[j] = f2b(o < 92 ? Watom[(size_t)o*64 + dbase + j] : 0.f);
  }
  *(uint4*)&prep[(size_t)idx*8] = *(const uint4*)tmp;
}

// ---------------- embedding (proven) ----------------
__global__ __launch_bounds__(256) void k_embed(const float* __restrict__ A, const float* __restrict__ W,
                                               float* __restrict__ fea){
  __shared__ float Wl[92][64];
  __shared__ float Al[64][92];
  int t = threadIdx.x;
  int base = blockIdx.x * 64;
  for (int i = t; i < 92*64; i += 256){ int d = i / 92, k = i - d*92; Wl[k][d] = W[d*92 + k]; }
  for (int i = t; i < 64*92; i += 256){ int a = i / 92, k = i - a*92; Al[a][k] = A[(size_t)(base+a)*92 + k]; }
  __syncthreads();
  int d = t & 63, slot = t >> 6;
  for (int a = slot; a < 64; a += 4){
    float acc = 0.f;
    #pragma unroll 4
    for (int k = 0; k < 92; k++) acc += Al[a][k] * Wl[k][d];
    fea[(size_t)(base+a)*64 + d] = acc;
  }
}

// ---------------- proj layer 0 (proven) ----------------
__global__ __launch_bounds__(256) void k_proj(const float* __restrict__ fea, const bf16* __restrict__ Wp,
                                              float* __restrict__ P){
  __shared__ bf16 Fb[64][72];
  int t = threadIdx.x, L = t & 63, w = t >> 6;
  int base = blockIdx.x * 64;
  for (int i = t; i < 4096; i += 256){ int r = i >> 6, d = i & 63;
    Fb[r][d] = f2b(fea[(size_t)(base+r)*64 + d]); }
  __syncthreads();
  short8v av0 = *(const short8v*)&Fb[w*16 + (L&15)][(L>>4)*8];
  short8v av1 = *(const short8v*)&Fb[w*16 + (L&15)][(L>>4)*8 + 32];
  #pragma unroll
  for (int tc = 0; tc < 16; tc++){
    short8v bv0 = *(const short8v*)&Wp[(size_t)((tc*2 + 0)*64 + L)*8];
    short8v bv1 = *(const short8v*)&Wp[(size_t)((tc*2 + 1)*64 + L)*8];
    f32x4 acc = (f32x4){0.f,0.f,0.f,0.f};
    acc = __builtin_amdgcn_mfma_f32_16x16x32_bf16(av0, bv0, acc, 0, 0, 0);
    acc = __builtin_amdgcn_mfma_f32_16x16x32_bf16(av1, bv1, acc, 0, 0, 0);
    #pragma unroll
    for (int r = 0; r < 4; r++){
      int m = base + w*16 + (L>>4)*4 + r;
      P[(size_t)m*256 + tc*16 + (L&15)] = acc[r];
    }
  }
}

// ---------------- proj with fused prev-layer update (proven) ----------------
__global__ __launch_bounds__(256) void k_proju(const float* __restrict__ fea_in, const float* __restrict__ summed,
    const float* __restrict__ sc2v, const float* __restrict__ sh2v, float* __restrict__ fea_out,
    const bf16* __restrict__ Wp, float* __restrict__ P){
  __shared__ bf16 Fb[64][72];
  __shared__ float scs[64], shs[64];
  int t = threadIdx.x, L = t & 63, w = t >> 6;
  int base = blockIdx.x * 64;
  if (t < 64){ scs[t] = sc2v[t]; shs[t] = sh2v[t]; }
  __syncthreads();
  for (int i = t; i < 4096; i += 256){
    int r = i >> 6, d = i & 63;
    size_t off = (size_t)(base+r)*64 + d;
    float x = softplus_f(fea_in[off] + summed[off]*scs[d] + shs[d]);
    fea_out[off] = x;
    Fb[r][d] = f2b(x);
  }
  __syncthreads();
  short8v av0 = *(const short8v*)&Fb[w*16 + (L&15)][(L>>4)*8];
  short8v av1 = *(const short8v*)&Fb[w*16 + (L&15)][(L>>4)*8 + 32];
  #pragma unroll
  for (int tc = 0; tc < 16; tc++){
    short8v bv0 = *(const short8v*)&Wp[(size_t)((tc*2 + 0)*64 + L)*8];
    short8v bv1 = *(const short8v*)&Wp[(size_t)((tc*2 + 1)*64 + L)*8];
    f32x4 acc = (f32x4){0.f,0.f,0.f,0.f};
    acc = __builtin_amdgcn_mfma_f32_16x16x32_bf16(av0, bv0, acc, 0, 0, 0);
    acc = __builtin_amdgcn_mfma_f32_16x16x32_bf16(av1, bv1, acc, 0, 0, 0);
    #pragma unroll
    for (int r = 0; r < 4; r++){
      int m = base + w*16 + (L>>4)*4 + r;
      P[(size_t)m*256 + tc*16 + (L&15)] = acc[r];
    }
  }
}

// ---------------- gate: round-3 access patterns, 2 channels/thread (halves LDS-pipe issue) ----------------
__global__ __launch_bounds__(256) void k_gate(const float* __restrict__ P, const float* __restrict__ nbrF,
    const int* __restrict__ idx, const float* __restrict__ W, const float* __restrict__ bg,
    bf16* __restrict__ gated, float* __restrict__ psum, float* __restrict__ psq){
  __shared__ float nf[48][44];
  __shared__ int jrow[48];
  __shared__ float red[256];
  int t = threadIdx.x;
  int slot = t >> 6, c = t & 63;            // wave = one slot; lanes = channels 0..63
  float wreg0[41], wreg1[41];
  #pragma unroll
  for (int e = 0; e < 41; e++){
    wreg0[e] = W[(size_t)c*169 + 128 + e];
    wreg1[e] = W[(size_t)(c+64)*169 + 128 + e];
  }
  float bv0 = bg[c], bv1 = bg[c + 64];
  float s0 = 0.f, q0 = 0.f, s1 = 0.f, q1 = 0.f;
  int rbase = blockIdx.x * 288;
  for (int st = 0; st < 6; st++){
    int row0 = rbase + st*48;
    __syncthreads();
    for (int i = t; i < 48*41; i += 256){ int rr = i / 41, e = i - rr*41; nf[rr][e] = nbrF[(size_t)(row0+rr)*41 + e]; }
    if (t < 48) jrow[t] = idx[row0 + t];
    __syncthreads();
    int a = row0/12 + slot;                 // rows of this slot share one atom
    float ps0 = P[(size_t)a*256 + c]      + bv0;
    float ps1 = P[(size_t)a*256 + 64 + c] + bv1;
    #pragma unroll
    for (int m = 0; m < 12; m++){
      int rr = slot*12 + m;
      int j = jrow[rr];
      float acc0 = ps0 + P[(size_t)j*256 + 128 + c];
      float acc1 = ps1 + P[(size_t)j*256 + 192 + c];
      #pragma unroll
      for (int eb = 0; eb < 10; eb++){
        float4 nv = *(const float4*)&nf[rr][eb*4];
        acc0 += nv.x*wreg0[eb*4] + nv.y*wreg0[eb*4+1] + nv.z*wreg0[eb*4+2] + nv.w*wreg0[eb*4+3];
        acc1 += nv.x*wreg1[eb*4] + nv.y*wreg1[eb*4+1] + nv.z*wreg1[eb*4+2] + nv.w*wreg1[eb*4+3];
      }
      float e40 = nf[rr][40];
      acc0 += e40 * wreg0[40];
      acc1 += e40 * wreg1[40];
      size_t go = (size_t)(row0 + rr)*128;
      gated[go + c]      = f2b(acc0);
      gated[go + 64 + c] = f2b(acc1);
      s0 += acc0; q0 += acc0*acc0;
      s1 += acc1; q1 += acc1*acc1;
    }
  }
  // stats: channel c partials from 4 slots, then channel c+64
  red[t] = s0; __syncthreads();
  if (t < 64) psum[blockIdx.x*128 + t] = red[t] + red[64+t] + red[128+t] + red[192+t];
  __syncthreads(); red[t] = s1; __syncthreads();
  if (t < 64) psum[blockIdx.x*128 + 64 + t] = red[t] + red[64+t] + red[128+t] + red[192+t];
  __syncthreads(); red[t] = q0; __syncthreads();
  if (t < 64) psq[blockIdx.x*128 + t] = red[t] + red[64+t] + red[128+t] + red[192+t];
  __syncthreads(); red[t] = q1; __syncthreads();
  if (t < 64) psq[blockIdx.x*128 + 64 + t] = red[t] + red[64+t] + red[128+t] + red[192+t];
}

// ---------------- parallel fins (proven) ----------------
__global__ __launch_bounds__(256) void k_fin1(const float* __restrict__ ps, const float* __restrict__ pq,
    const float* __restrict__ g, const float* __restrict__ be, float* __restrict__ scale, float* __restrict__ shift){
  __shared__ float rs[256], rq[256];
  int c = blockIdx.x, t = threadIdx.x;
  float s = 0.f, q = 0.f;
  for (int b = t; b < 1024; b += 256){ s += ps[b*128 + c]; q += pq[b*128 + c]; }
  rs[t] = s; rq[t] = q; __syncthreads();
  for (int o = 128; o > 0; o >>= 1){
    if (t < o){ rs[t] += rs[t+o]; rq[t] += rq[t+o]; }
    __syncthreads();
  }
  if (t == 0){
    float cnt = 294912.0f;
    float mu = rs[0] / cnt;
    float var = rq[0] / cnt - mu*mu;
    float sc = rsqrtf(var + 1e-5f) * g[c];
    scale[c] = sc;
    shift[c] = be[c] - mu * sc;
  }
}

__global__ __launch_bounds__(256) void k_fin2(const float* __restrict__ ps, const float* __restrict__ pq,
    const float* __restrict__ g, const float* __restrict__ be, float* __restrict__ scale, float* __restrict__ shift){
  __shared__ float rs[256], rq[256];
  int c = blockIdx.x, t = threadIdx.x;
  float s = 0.f, q = 0.f;
  for (int b = t; b < 768; b += 256){ s += ps[b*64 + c]; q += pq[b*64 + c]; }
  rs[t] = s; rq[t] = q; __syncthreads();
  for (int o = 128; o > 0; o >>= 1){
    if (t < o){ rs[t] += rs[t+o]; rq[t] += rq[t+o]; }
    __syncthreads();
  }
  if (t == 0){
    float cnt = 24576.0f;
    float mu = rs[0] / cnt;
    float var = rq[0] / cnt - mu*mu;
    float sc = rsqrtf(var + 1e-5f) * g[c];
    scale[c] = sc;
    shift[c] = be[c] - mu * sc;
  }
}

// ---------------- pool (proven, FROZEN) ----------------
__global__ __launch_bounds__(256) void k_pool(const bf16* __restrict__ gated, const float* __restrict__ scale,
    const float* __restrict__ shift, float* __restrict__ summed, float* __restrict__ psum, float* __restrict__ psq){
  __shared__ float sc[128], sh[128];
  __shared__ float sb[32][65], qb[32][65];
  int t = threadIdx.x;
  if (t < 128){ sc[t] = scale[t]; sh[t] = shift[t]; }
  __syncthreads();
  int nl = t >> 3, jb = t & 7;
  int n = blockIdx.x*32 + nl;
  const bf16* gp = gated + (size_t)n*1536 + jb*8;
  float sc1r[8], sh1r[8], sc2r[8], sh2r[8];
  #pragma unroll
  for (int k = 0; k < 8; k++){
    int d = jb*8 + k;
    sc1r[k] = sc[d]; sh1r[k] = sh[d]; sc2r[k] = sc[64+d]; sh2r[k] = sh[64+d];
  }
  float acc[8];
  #pragma unroll
  for (int k = 0; k < 8; k++) acc[k] = 0.f;
  #pragma unroll
  for (int m = 0; m < 12; m++){
    short8v fv = *(const short8v*)(gp + m*128);
    short8v cv = *(const short8v*)(gp + m*128 + 64);
    #pragma unroll
    for (int k = 0; k < 8; k++){
      bf16 fb, cb;
      *(short*)&fb = fv[k]; *(short*)&cb = cv[k];
      float y1 = b2f(fb) * sc1r[k] + sh1r[k];
      float y2 = b2f(cb) * sc2r[k] + sh2r[k];
      acc[k] += sigmoid_f(y1) * softplus_f(y2);
    }
  }
  float* sp = &summed[(size_t)n*64 + jb*8];
  *(float4*)(sp+0) = make_float4(acc[0], acc[1], acc[2], acc[3]);
  *(float4*)(sp+4) = make_float4(acc[4], acc[5], acc[6], acc[7]);
  #pragma unroll
  for (int k = 0; k < 8; k++){ sb[nl][jb*8+k] = acc[k]; qb[nl][jb*8+k] = acc[k]*acc[k]; }
  __syncthreads();
  if (t < 64){
    float S = 0.f, Q = 0.f;
    #pragma unroll 4
    for (int nn = 0; nn < 32; nn++){ S += sb[nn][t]; Q += qb[nn][t]; }
    psum[blockIdx.x*64 + t] = S;
    psq [blockIdx.x*64 + t] = Q;
  }
}

// ================= decode stage 1 + fused final update (proven) =================
__global__ __launch_bounds__(256) void k_zfillu(const float* __restrict__ fea_in, const float* __restrict__ summed,
    const float* __restrict__ sc2v, const float* __restrict__ sh2v, float* __restrict__ fea_out,
    const int* __restrict__ cidx, const bf16* __restrict__ We, bf16* __restrict__ Zfrag){
  __shared__ bf16 btb[48][72];
  __shared__ float scs[64], shs[64];
  int b = blockIdx.x;
  int t = threadIdx.x, L = t & 63, w = t >> 6;
  const int* ci = cidx + b*48;
  if (t < 64){ scs[t] = sc2v[t]; shs[t] = sh2v[t]; }
  __syncthreads();
  for (int i = t; i < 3072; i += 256){
    int r = i>>6, d = i&63;
    size_t off = (size_t)ci[r]*64 + d;
    float x = softplus_f(fea_in[off] + summed[off]*scs[d] + shs[d]);
    fea_out[off] = x;
    btb[r][d] = f2b(x);
  }
  __syncthreads();
  bf16* Zb_base = Zfrag + (size_t)b*33792;
  int d0 = w*16 + (L >> 4)*4;
  int dc = d0 >> 5, sub = (d0 >> 3) & 3, off2 = d0 & 7;
  #pragma unroll
  for (int k = 0; k < 11; k++){
    short8v av0 = *(const short8v*)&We[(size_t)(k*512 + (w*2 + 0)*64 + L)*8];
    short8v av1 = *(const short8v*)&We[(size_t)(k*512 + (w*2 + 1)*64 + L)*8];
    bf16* Zb = Zb_base + (size_t)k*3072;
    #pragma unroll
    for (int nc = 0; nc < 3; nc++){
      short8v bv0 = *(const short8v*)&btb[nc*16 + (L&15)][(L>>4)*8];
      short8v bv1 = *(const short8v*)&btb[nc*16 + (L&15)][(L>>4)*8 + 32];
      f32x4 z = (f32x4){0.f,0.f,0.f,0.f};
      z = __builtin_amdgcn_mfma_f32_16x16x32_bf16(av0, bv0, z, 0, 0, 0);
      z = __builtin_amdgcn_mfma_f32_16x16x32_bf16(av1, bv1, z, 0, 0, 0);
      bf16 zp[4];
      #pragma unroll
      for (int r = 0; r < 4; r++) zp[r] = f2b(z[r]);
      *(uint2*)&Zb[(size_t)((nc*2 + dc)*64 + sub*16 + (L&15))*8 + off2] = *(const uint2*)zp;
    }
  }
}

// ================= decode stage 2 (proven, FROZEN) =================
__global__ __launch_bounds__(256) void k_pair(const float* __restrict__ fea, const int* __restrict__ cidx,
    const bf16* __restrict__ Zfrag, const bf16* __restrict__ Waf,
    const float* __restrict__ badj, const float* __restrict__ Wfc1, const float* __restrict__ bfc1,
    const float* __restrict__ bedge, const float* __restrict__ Wfc2, const float* __restrict__ bfc2,
    const float* __restrict__ batom, float* __restrict__ out){
  __shared__ float cst[84];
  int t = threadIdx.x, L = t & 63, w = t >> 6;
  int bx = blockIdx.x, b = bx / 3, mr = bx - b*3;
  if (t < 36) cst[t] = Wfc1[t];
  else if (t < 42) cst[t] = bfc1[t-36];
  else if (t < 48) cst[t] = badj[t-42];
  else if (t < 73) cst[t] = Wfc2[t-48];
  else if (t < 78) cst[t] = bfc2[t-73];
  else if (t < 83) cst[t] = bedge[t-78];
  int arow = cidx[b*48 + mr*16 + (L & 15)];
  const float* fr = fea + (size_t)arow*64 + (L >> 4)*8;
  float fa[16];
  *(float4*)(fa+0)  = *(const float4*)(fr+0);
  *(float4*)(fa+4)  = *(const float4*)(fr+4);
  *(float4*)(fa+8)  = *(const float4*)(fr+32);
  *(float4*)(fa+12) = *(const float4*)(fr+36);
  bf16 ab[16];
  #pragma unroll
  for (int j = 0; j < 16; j++) ab[j] = f2b(fa[j]);
  short8v av0 = *(const short8v*)&ab[0];
  short8v av1 = *(const short8v*)&ab[8];
  __syncthreads();

  if (w < 3){
    const bf16* Zb = Zfrag + (size_t)b*33792 + (size_t)w*1024;
    f32x4 acc[11];
    #pragma unroll
    for (int k = 0; k < 11; k++){
      const bf16* zp = Zb + (size_t)k*3072;
      short8v bv0 = *(const short8v*)&zp[(size_t)L*8];
      short8v bv1 = *(const short8v*)&zp[512 + (size_t)L*8];
      f32x4 a = (f32x4){0.f,0.f,0.f,0.f};
      a = __builtin_amdgcn_mfma_f32_16x16x32_bf16(av0, bv0, a, 0, 0, 0);
      a = __builtin_amdgcn_mfma_f32_16x16x32_bf16(av1, bv1, a, 0, 0, 0);
      acc[k] = a;
    }
    size_t obase = (size_t)b * 13824;
    size_t fbase = 9338880ull + (size_t)b * 11520;
    int n = w*16 + (L & 15);
    #pragma unroll
    for (int r = 0; r < 4; r++){
      int m = mr*16 + (L >> 4)*4 + r;
      float sv[6];
      #pragma unroll
      for (int k = 0; k < 6; k++) sv[k] = acc[k][r] + cst[42 + k];
      float v[6]; float mx = -1e30f;
      #pragma unroll
      for (int i2 = 0; i2 < 6; i2++){
        float a = cst[36 + i2];
        #pragma unroll
        for (int j2 = 0; j2 < 6; j2++) a += cst[i2*6 + j2] * sv[j2];
        v[i2] = a; mx = fmaxf(mx, a);
      }
      float lse = 0.f;
      #pragma unroll
      for (int i2 = 0; i2 < 6; i2++) lse += __expf(v[i2] - mx);
      lse = mx + __logf(lse);
      size_t po = obase + (size_t)(m*48 + n)*6;
      #pragma unroll
      for (int i2 = 0; i2 < 6; i2++) out[po + i2] = v[i2] - lse;
      float sf[5];
      #pragma unroll
      for (int k = 0; k < 5; k++) sf[k] = acc[6 + k][r] + cst[78 + k];
      size_t pf = fbase + (size_t)(m*48 + n)*5;
      #pragma unroll
      for (int i2 = 0; i2 < 5; i2++){
        float a = cst[73 + i2];
        #pragma unroll
        for (int j2 = 0; j2 < 5; j2++) a += cst[48 + i2*5 + j2] * sf[j2];
        out[pf + i2] = a;
      }
    }
  } else {
    size_t abase = 7077888ull + (size_t)b * 4416;
    #pragma unroll
    for (int oc = 0; oc < 6; oc++){
      short8v bv0 = *(const short8v*)&Waf[(size_t)((oc*2 + 0)*64 + L)*8];
      short8v bv1 = *(const short8v*)&Waf[(size_t)((oc*2 + 1)*64 + L)*8];
      f32x4 a = (f32x4){0.f,0.f,0.f,0.f};
      a = __builtin_amdgcn_mfma_f32_16x16x32_bf16(av0, bv0, a, 0, 0, 0);
      a = __builtin_amdgcn_mfma_f32_16x16x32_bf16(av1, bv1, a, 0, 0, 0);
      int o = oc*16 + (L & 15);
      if (o < 92){
        float bb2 = batom[o];
        #pragma unroll
        for (int r = 0; r < 4; r++){
          int m = mr*16 + (L >> 4)*4 + r;
          out[abase + (size_t)m*92 + o] = a[r] + bb2;
        }
      }
    }
  }
}

extern "C" void kernel_launch(void* const* d_in, const int* in_sizes, int n_in,
                              void* d_out, int out_size, void* d_ws, size_t ws_size,
                              hipStream_t stream) {
  const float* atom_fea = (const float*)d_in[0];
  const float* nbr_fea  = (const float*)d_in[1];
  const int*   nbr_idx  = (const int*)d_in[2];
  const int*   cidx     = (const int*)d_in[3];
  const float* W_emb    = (const float*)d_in[4];
  const float* W_full   = (const float*)d_in[5];
  const float* b_full   = (const float*)d_in[6];
  const float* g1       = (const float*)d_in[7];
  const float* be1      = (const float*)d_in[8];
  const float* g2       = (const float*)d_in[9];
  const float* be2      = (const float*)d_in[10];
  const float* W_adj    = (const float*)d_in[11];
  const float* b_adj    = (const float*)d_in[12];
  const float* W_fc1    = (const float*)d_in[13];
  const float* b_fc1    = (const float*)d_in[14];
  const float* W_edge   = (const float*)d_in[15];
  const float* b_edge   = (const float*)d_in[16];
  const float* W_fc2    = (const float*)d_in[17];
  const float* b_fc2    = (const float*)d_in[18];
  const float* W_atom   = (const float*)d_in[19];
  const float* b_atom   = (const float*)d_in[20];

  char* ws = (char*)d_ws;
  float* feaA   = (float*)(ws);                  // 6,291,456
  float* feaB   = (float*)(ws + 6291456);        // 6,291,456
  float* P      = (float*)(ws + 12582912);       // 25,165,824
  float* p2     = (float*)(ws + 12582912);       // aliases P head (P dead during pool/fin2)
  float* p2q    = (float*)(ws + 12779520);       // aliases P
  float* summed = (float*)(ws + 37748736);       // 6,291,456
  float* p1     = (float*)(ws + 44040192);       // 524,288 (1024 x 128)
  float* p1q    = (float*)(ws + 44564480);       // 524,288
  float* sc1    = (float*)(ws + 45088768);       // 512
  float* sh1    = (float*)(ws + 45089280);       // 512
  float* sc2    = (float*)(ws + 45089792);       // 256
  float* sh2    = (float*)(ws + 45090048);       // 256
  bf16*  prep   = (bf16*) (ws + 45090304);       // 249,856
  bf16*  gated  = (bf16*) (ws + 45340160);       // 75,497,472 (end 120,837,632)
  bf16*  Zfrag  = gated;                         // reuses gated (dead by decode)
  float* out    = (float*)d_out;

  bf16* prepProj = prep;                // + l*16384
  bf16* prepEdge = prep + 73728;
  bf16* prepAtom = prep + 118784;

  k_prep_w<<<61, 256, 0, stream>>>(W_full, W_adj, W_edge, W_atom, prep);
  k_embed<<<384, 256, 0, stream>>>(atom_fea, W_emb, feaA);

  // layer 0
  k_proj<<<384, 256, 0, stream>>>(feaA, prepProj, P);
  k_gate<<<1024, 256, 0, stream>>>(P, nbr_fea, nbr_idx, W_full, b_full, gated, p1, p1q);
  k_fin1<<<128, 256, 0, stream>>>(p1, p1q, g1, be1, sc1, sh1);
  k_pool<<<768, 256, 0, stream>>>(gated, sc1, sh1, summed, p2, p2q);
  k_fin2<<<64, 256, 0, stream>>>(p2, p2q, g2, be2, sc2, sh2);

  // layer 1 (update_0 fused into proju)
  k_proju<<<384, 256, 0, stream>>>(feaA, summed, sc2, sh2, feaB, prepProj + 16384, P);
  k_gate<<<1024, 256, 0, stream>>>(P, nbr_fea, nbr_idx, W_full + 21632, b_full + 128, gated, p1, p1q);
  k_fin1<<<128, 256, 0, stream>>>(p1, p1q, g1 + 128, be1 + 128, sc1, sh1);
  k_pool<<<768, 256, 0, stream>>>(gated, sc1, sh1, summed, p2, p2q);
  k_fin2<<<64, 256, 0, stream>>>(p2, p2q, g2 + 64, be2 + 64, sc2, sh2);

  // layer 2 (update_1 fused into proju)
  k_proju<<<384, 256, 0, stream>>>(feaB, summed, sc2, sh2, feaA, prepProj + 32768, P);
  k_gate<<<1024, 256, 0, stream>>>(P, nbr_fea, nbr_idx, W_full + 43264, b_full + 256, gated, p1, p1q);
  k_fin1<<<128, 256, 0, stream>>>(p1, p1q, g1 + 256, be1 + 256, sc1, sh1);
  k_pool<<<768, 256, 0, stream>>>(gated, sc1, sh1, summed, p2, p2q);
  k_fin2<<<64, 256, 0, stream>>>(p2, p2q, g2 + 128, be2 + 128, sc2, sh2);

  // decode (update_2 fused into zfillu; fea3 written to feaB for k_pair)
  k_zfillu<<<512, 256, 0, stream>>>(feaA, summed, sc2, sh2, feaB, cidx, prepEdge, Zfrag);
  k_pair<<<1536, 256, 0, stream>>>(feaB, cidx, Zfrag, prepAtom, b_adj, W_fc1, b_fc1,
                                   b_edge, W_fc2, b_fc2, b_atom, out);
}

// Round 15
// 468.117 us; speedup vs baseline: 1.0981x; 1.0981x over previous
//
#include <hip/hip_runtime.h>
#include <hip/hip_bf16.h>

typedef __hip_bfloat16 bf16;
typedef __attribute__((ext_vector_type(8))) short short8v;
typedef __attribute__((ext_vector_type(4))) float f32x4;

__device__ __forceinline__ float b2f(bf16 v){ return __bfloat162float(v); }
__device__ __forceinline__ bf16 f2b(float v){ return __float2bfloat16(v); }
__device__ __forceinline__ float softplus_f(float x){ return (x > 15.f) ? x : __logf(1.f + __expf(x)); }
__device__ __forceinline__ float sigmoid_f(float x){ return 1.f / (1.f + __expf(-x)); }

// ---------------- one-shot weight -> MFMA-fragment precompute (proven) ----------------
__global__ __launch_bounds__(256) void k_prep_w(const float* __restrict__ Wfull, const float* __restrict__ Wadj,
    const float* __restrict__ Wedge, const float* __restrict__ Watom, bf16* __restrict__ prep){
  int idx = blockIdx.x*256 + threadIdx.x;
  if (idx >= 15616) return;
  bf16 tmp[8];
  if (idx < 6144){
    int l = idx >> 11, rem = idx & 2047;
    int tc = rem >> 7, h = (rem >> 6) & 1, L = rem & 63;
    int rw = tc*16 + (L & 15);
    int c = rw & 127;
    int e0 = ((rw < 128) ? 0 : 64) + h*32 + ((L >> 4)*8);
    const float* src = Wfull + (size_t)l*21632 + (size_t)c*169 + e0;
    #pragma unroll
    for (int j = 0; j < 8; j++) tmp[j] = f2b(src[j]);
  } else if (idx < 9216){
    int u = idx - 6144;
    int l = u >> 10, rem = u & 1023;
    int tc = rem >> 7, h = (rem >> 6) & 1, L = rem & 63;
    int c = tc*16 + (L & 15);
    int k0 = h*32 + ((L >> 4)*8);
    #pragma unroll
    for (int j = 0; j < 8; j++){
      int k = k0 + j;
      tmp[j] = f2b(k < 41 ? Wfull[(size_t)l*21632 + (size_t)c*169 + 128 + k] : 0.f);
    }
  } else if (idx < 14848){
    int u = idx - 9216;
    int k = u >> 9, rem = u & 511;
    int w = rem >> 7, h = (rem >> 6) & 1, L = rem & 63;
    const float* Wk = (k < 6) ? (Wadj + (size_t)k*4096) : (Wedge + (size_t)(k-6)*4096);
    int row = w*16 + (L & 15);
    int e0 = h*32 + ((L >> 4)*8);
    #pragma unroll
    for (int j = 0; j < 8; j++) tmp[j] = f2b(Wk[(size_t)row*64 + e0 + j]);
  } else {
    int u = idx - 14848;
    int oc = u >> 7, dc = (u >> 6) & 1, L = u & 63;
    int o = oc*16 + (L & 15);
    int dbase = ((L >> 4)*8) + dc*32;
    #pragma unroll
    for (int j = 0; j < 8; j++) tmp[j] = f2b(o < 92 ? Watom[(size_t)o*64 + dbase + j] : 0.f);
  }
  *(uint4*)&prep[(size_t)idx*8] = *(const uint4*)tmp;
}

// ---------------- embedding (proven) ----------------
__global__ __launch_bounds__(256) void k_embed(const float* __restrict__ A, const float* __restrict__ W,
                                               float* __restrict__ fea){
  __shared__ float Wl[92][64];
  __shared__ float Al[64][92];
  int t = threadIdx.x;
  int base = blockIdx.x * 64;
  for (int i = t; i < 92*64; i += 256){ int d = i / 92, k = i - d*92; Wl[k][d] = W[d*92 + k]; }
  for (int i = t; i < 64*92; i += 256){ int a = i / 92, k = i - a*92; Al[a][k] = A[(size_t)(base+a)*92 + k]; }
  __syncthreads();
  int d = t & 63, slot = t >> 6;
  for (int a = slot; a < 64; a += 4){
    float acc = 0.f;
    #pragma unroll 4
    for (int k = 0; k < 92; k++) acc += Al[a][k] * Wl[k][d];
    fea[(size_t)(base+a)*64 + d] = acc;
  }
}

// ---------------- proj layer 0 (proven) ----------------
__global__ __launch_bounds__(256) void k_proj(const float* __restrict__ fea, const bf16* __restrict__ Wp,
                                              float* __restrict__ P){
  __shared__ bf16 Fb[64][72];
  int t = threadIdx.x, L = t & 63, w = t >> 6;
  int base = blockIdx.x * 64;
  for (int i = t; i < 4096; i += 256){ int r = i >> 6, d = i & 63;
    Fb[r][d] = f2b(fea[(size_t)(base+r)*64 + d]); }
  __syncthreads();
  short8v av0 = *(const short8v*)&Fb[w*16 + (L&15)][(L>>4)*8];
  short8v av1 = *(const short8v*)&Fb[w*16 + (L&15)][(L>>4)*8 + 32];
  #pragma unroll
  for (int tc = 0; tc < 16; tc++){
    short8v bv0 = *(const short8v*)&Wp[(size_t)((tc*2 + 0)*64 + L)*8];
    short8v bv1 = *(const short8v*)&Wp[(size_t)((tc*2 + 1)*64 + L)*8];
    f32x4 acc = (f32x4){0.f,0.f,0.f,0.f};
    acc = __builtin_amdgcn_mfma_f32_16x16x32_bf16(av0, bv0, acc, 0, 0, 0);
    acc = __builtin_amdgcn_mfma_f32_16x16x32_bf16(av1, bv1, acc, 0, 0, 0);
    #pragma unroll
    for (int r = 0; r < 4; r++){
      int m = base + w*16 + (L>>4)*4 + r;
      P[(size_t)m*256 + tc*16 + (L&15)] = acc[r];
    }
  }
}

// ---------------- proj with fused prev-layer update (proven) ----------------
__global__ __launch_bounds__(256) void k_proju(const float* __restrict__ fea_in, const float* __restrict__ summed,
    const float* __restrict__ sc2v, const float* __restrict__ sh2v, float* __restrict__ fea_out,
    const bf16* __restrict__ Wp, float* __restrict__ P){
  __shared__ bf16 Fb[64][72];
  __shared__ float scs[64], shs[64];
  int t = threadIdx.x, L = t & 63, w = t >> 6;
  int base = blockIdx.x * 64;
  if (t < 64){ scs[t] = sc2v[t]; shs[t] = sh2v[t]; }
  __syncthreads();
  for (int i = t; i < 4096; i += 256){
    int r = i >> 6, d = i & 63;
    size_t off = (size_t)(base+r)*64 + d;
    float x = softplus_f(fea_in[off] + summed[off]*scs[d] + shs[d]);
    fea_out[off] = x;
    Fb[r][d] = f2b(x);
  }
  __syncthreads();
  short8v av0 = *(const short8v*)&Fb[w*16 + (L&15)][(L>>4)*8];
  short8v av1 = *(const short8v*)&Fb[w*16 + (L&15)][(L>>4)*8 + 32];
  #pragma unroll
  for (int tc = 0; tc < 16; tc++){
    short8v bv0 = *(const short8v*)&Wp[(size_t)((tc*2 + 0)*64 + L)*8];
    short8v bv1 = *(const short8v*)&Wp[(size_t)((tc*2 + 1)*64 + L)*8];
    f32x4 acc = (f32x4){0.f,0.f,0.f,0.f};
    acc = __builtin_amdgcn_mfma_f32_16x16x32_bf16(av0, bv0, acc, 0, 0, 0);
    acc = __builtin_amdgcn_mfma_f32_16x16x32_bf16(av1, bv1, acc, 0, 0, 0);
    #pragma unroll
    for (int r = 0; r < 4; r++){
      int m = base + w*16 + (L>>4)*4 + r;
      P[(size_t)m*256 + tc*16 + (L&15)] = acc[r];
    }
  }
}

// ---------------- gate (round-3 exact, FROZEN — 6 restructures all regressed) ----------------
__global__ __launch_bounds__(256) void k_gate(const float* __restrict__ P, const float* __restrict__ nbrF,
    const int* __restrict__ idx, const float* __restrict__ W, const float* __restrict__ bg,
    bf16* __restrict__ gated, float* __restrict__ psum, float* __restrict__ psq){
  __shared__ float nf[24][44];
  __shared__ int jrow[24];
  __shared__ float red[256];
  int t = threadIdx.x;
  int slot = t >> 7, c = t & 127;
  float wreg[41];
  #pragma unroll
  for (int e = 0; e < 41; e++) wreg[e] = W[(size_t)c*169 + 128 + e];
  float bv = bg[c];
  float s = 0.f, q = 0.f;
  int rbase = blockIdx.x * 288;
  for (int st = 0; st < 12; st++){
    int row0 = rbase + st*24;
    __syncthreads();
    for (int i = t; i < 24*41; i += 256){ int rr = i / 41, e = i - rr*41; nf[rr][e] = nbrF[(size_t)(row0+rr)*41 + e]; }
    if (t < 24) jrow[t] = idx[row0 + t];
    __syncthreads();
    int a = row0/12 + slot;
    float ps = P[(size_t)a*256 + c] + bv;
    #pragma unroll
    for (int m = 0; m < 12; m++){
      int rr = slot*12 + m;
      int j = jrow[rr];
      float acc = ps + P[(size_t)j*256 + 128 + c];
      #pragma unroll
      for (int eb = 0; eb < 10; eb++){
        float4 nv = *(const float4*)&nf[rr][eb*4];
        acc += nv.x*wreg[eb*4] + nv.y*wreg[eb*4+1] + nv.z*wreg[eb*4+2] + nv.w*wreg[eb*4+3];
      }
      acc += nf[rr][40] * wreg[40];
      gated[(size_t)(row0+rr)*128 + c] = f2b(acc);
      s += acc; q += acc*acc;
    }
  }
  red[t] = s; __syncthreads();
  if (t < 128) psum[blockIdx.x*128 + t] = red[t] + red[t+128];
  __syncthreads(); red[t] = q; __syncthreads();
  if (t < 128) psq[blockIdx.x*128 + t] = red[t] + red[t+128];
}

// ---------------- parallel fins (proven) ----------------
__global__ __launch_bounds__(256) void k_fin1(const float* __restrict__ ps, const float* __restrict__ pq,
    const float* __restrict__ g, const float* __restrict__ be, float* __restrict__ scale, float* __restrict__ shift){
  __shared__ float rs[256], rq[256];
  int c = blockIdx.x, t = threadIdx.x;
  float s = 0.f, q = 0.f;
  for (int b = t; b < 1024; b += 256){ s += ps[b*128 + c]; q += pq[b*128 + c]; }
  rs[t] = s; rq[t] = q; __syncthreads();
  for (int o = 128; o > 0; o >>= 1){
    if (t < o){ rs[t] += rs[t+o]; rq[t] += rq[t+o]; }
    __syncthreads();
  }
  if (t == 0){
    float cnt = 294912.0f;
    float mu = rs[0] / cnt;
    float var = rq[0] / cnt - mu*mu;
    float sc = rsqrtf(var + 1e-5f) * g[c];
    scale[c] = sc;
    shift[c] = be[c] - mu * sc;
  }
}

__global__ __launch_bounds__(256) void k_fin2(const float* __restrict__ ps, const float* __restrict__ pq,
    const float* __restrict__ g, const float* __restrict__ be, float* __restrict__ scale, float* __restrict__ shift){
  __shared__ float rs[256], rq[256];
  int c = blockIdx.x, t = threadIdx.x;
  float s = 0.f, q = 0.f;
  for (int b = t; b < 768; b += 256){ s += ps[b*64 + c]; q += pq[b*64 + c]; }
  rs[t] = s; rq[t] = q; __syncthreads();
  for (int o = 128; o > 0; o >>= 1){
    if (t < o){ rs[t] += rs[t+o]; rq[t] += rq[t+o]; }
    __syncthreads();
  }
  if (t == 0){
    float cnt = 24576.0f;
    float mu = rs[0] / cnt;
    float var = rq[0] / cnt - mu*mu;
    float sc = rsqrtf(var + 1e-5f) * g[c];
    scale[c] = sc;
    shift[c] = be[c] - mu * sc;
  }
}

// ---------------- pool (proven, FROZEN) ----------------
__global__ __launch_bounds__(256) void k_pool(const bf16* __restrict__ gated, const float* __restrict__ scale,
    const float* __restrict__ shift, float* __restrict__ summed, float* __restrict__ psum, float* __restrict__ psq){
  __shared__ float sc[128], sh[128];
  __shared__ float sb[32][65], qb[32][65];
  int t = threadIdx.x;
  if (t < 128){ sc[t] = scale[t]; sh[t] = shift[t]; }
  __syncthreads();
  int nl = t >> 3, jb = t & 7;
  int n = blockIdx.x*32 + nl;
  const bf16* gp = gated + (size_t)n*1536 + jb*8;
  float sc1r[8], sh1r[8], sc2r[8], sh2r[8];
  #pragma unroll
  for (int k = 0; k < 8; k++){
    int d = jb*8 + k;
    sc1r[k] = sc[d]; sh1r[k] = sh[d]; sc2r[k] = sc[64+d]; sh2r[k] = sh[64+d];
  }
  float acc[8];
  #pragma unroll
  for (int k = 0; k < 8; k++) acc[k] = 0.f;
  #pragma unroll
  for (int m = 0; m < 12; m++){
    short8v fv = *(const short8v*)(gp + m*128);
    short8v cv = *(const short8v*)(gp + m*128 + 64);
    #pragma unroll
    for (int k = 0; k < 8; k++){
      bf16 fb, cb;
      *(short*)&fb = fv[k]; *(short*)&cb = cv[k];
      float y1 = b2f(fb) * sc1r[k] + sh1r[k];
      float y2 = b2f(cb) * sc2r[k] + sh2r[k];
      acc[k] += sigmoid_f(y1) * softplus_f(y2);
    }
  }
  float* sp = &summed[(size_t)n*64 + jb*8];
  *(float4*)(sp+0) = make_float4(acc[0], acc[1], acc[2], acc[3]);
  *(float4*)(sp+4) = make_float4(acc[4], acc[5], acc[6], acc[7]);
  #pragma unroll
  for (int k = 0; k < 8; k++){ sb[nl][jb*8+k] = acc[k]; qb[nl][jb*8+k] = acc[k]*acc[k]; }
  __syncthreads();
  if (t < 64){
    float S = 0.f, Q = 0.f;
    #pragma unroll 4
    for (int nn = 0; nn < 32; nn++){ S += sb[nn][t]; Q += qb[nn][t]; }
    psum[blockIdx.x*64 + t] = S;
    psq [blockIdx.x*64 + t] = Q;
  }
}

// ================= decode stage 1 + fused final update (proven) =================
__global__ __launch_bounds__(256) void k_zfillu(const float* __restrict__ fea_in, const float* __restrict__ summed,
    const float* __restrict__ sc2v, const float* __restrict__ sh2v, float* __restrict__ fea_out,
    const int* __restrict__ cidx, const bf16* __restrict__ We, bf16* __restrict__ Zfrag){
  __shared__ bf16 btb[48][72];
  __shared__ float scs[64], shs[64];
  int b = blockIdx.x;
  int t = threadIdx.x, L = t & 63, w = t >> 6;
  const int* ci = cidx + b*48;
  if (t < 64){ scs[t] = sc2v[t]; shs[t] = sh2v[t]; }
  __syncthreads();
  for (int i = t; i < 3072; i += 256){
    int r = i>>6, d = i&63;
    size_t off = (size_t)ci[r]*64 + d;
    float x = softplus_f(fea_in[off] + summed[off]*scs[d] + shs[d]);
    fea_out[off] = x;
    btb[r][d] = f2b(x);
  }
  __syncthreads();
  bf16* Zb_base = Zfrag + (size_t)b*33792;
  int d0 = w*16 + (L >> 4)*4;
  int dc = d0 >> 5, sub = (d0 >> 3) & 3, off2 = d0 & 7;
  #pragma unroll
  for (int k = 0; k < 11; k++){
    short8v av0 = *(const short8v*)&We[(size_t)(k*512 + (w*2 + 0)*64 + L)*8];
    short8v av1 = *(const short8v*)&We[(size_t)(k*512 + (w*2 + 1)*64 + L)*8];
    bf16* Zb = Zb_base + (size_t)k*3072;
    #pragma unroll
    for (int nc = 0; nc < 3; nc++){
      short8v bv0 = *(const short8v*)&btb[nc*16 + (L&15)][(L>>4)*8];
      short8v bv1 = *(const short8v*)&btb[nc*16 + (L&15)][(L>>4)*8 + 32];
      f32x4 z = (f32x4){0.f,0.f,0.f,0.f};
      z = __builtin_amdgcn_mfma_f32_16x16x32_bf16(av0, bv0, z, 0, 0, 0);
      z = __builtin_amdgcn_mfma_f32_16x16x32_bf16(av1, bv1, z, 0, 0, 0);
      bf16 zp[4];
      #pragma unroll
      for (int r = 0; r < 4; r++) zp[r] = f2b(z[r]);
      *(uint2*)&Zb[(size_t)((nc*2 + dc)*64 + sub*16 + (L&15))*8 + off2] = *(const uint2*)zp;
    }
  }
}

// ================= decode stage 2 (proven, FROZEN) =================
__global__ __launch_bounds__(256) void k_pair(const float* __restrict__ fea, const int* __restrict__ cidx,
    const bf16* __restrict__ Zfrag, const bf16* __restrict__ Waf,
    const float* __restrict__ badj, const float* __restrict__ Wfc1, const float* __restrict__ bfc1,
    const float* __restrict__ bedge, const float* __restrict__ Wfc2, const float* __restrict__ bfc2,
    const float* __restrict__ batom, float* __restrict__ out){
  __shared__ float cst[84];
  int t = threadIdx.x, L = t & 63, w = t >> 6;
  int bx = blockIdx.x, b = bx / 3, mr = bx - b*3;
  if (t < 36) cst[t] = Wfc1[t];
  else if (t < 42) cst[t] = bfc1[t-36];
  else if (t < 48) cst[t] = badj[t-42];
  else if (t < 73) cst[t] = Wfc2[t-48];
  else if (t < 78) cst[t] = bfc2[t-73];
  else if (t < 83) cst[t] = bedge[t-78];
  int arow = cidx[b*48 + mr*16 + (L & 15)];
  const float* fr = fea + (size_t)arow*64 + (L >> 4)*8;
  float fa[16];
  *(float4*)(fa+0)  = *(const float4*)(fr+0);
  *(float4*)(fa+4)  = *(const float4*)(fr+4);
  *(float4*)(fa+8)  = *(const float4*)(fr+32);
  *(float4*)(fa+12) = *(const float4*)(fr+36);
  bf16 ab[16];
  #pragma unroll
  for (int j = 0; j < 16; j++) ab[j] = f2b(fa[j]);
  short8v av0 = *(const short8v*)&ab[0];
  short8v av1 = *(const short8v*)&ab[8];
  __syncthreads();

  if (w < 3){
    const bf16* Zb = Zfrag + (size_t)b*33792 + (size_t)w*1024;
    f32x4 acc[11];
    #pragma unroll
    for (int k = 0; k < 11; k++){
      const bf16* zp = Zb + (size_t)k*3072;
      short8v bv0 = *(const short8v*)&zp[(size_t)L*8];
      short8v bv1 = *(const short8v*)&zp[512 + (size_t)L*8];
      f32x4 a = (f32x4){0.f,0.f,0.f,0.f};
      a = __builtin_amdgcn_mfma_f32_16x16x32_bf16(av0, bv0, a, 0, 0, 0);
      a = __builtin_amdgcn_mfma_f32_16x16x32_bf16(av1, bv1, a, 0, 0, 0);
      acc[k] = a;
    }
    size_t obase = (size_t)b * 13824;
    size_t fbase = 9338880ull + (size_t)b * 11520;
    int n = w*16 + (L & 15);
    #pragma unroll
    for (int r = 0; r < 4; r++){
      int m = mr*16 + (L >> 4)*4 + r;
      float sv[6];
      #pragma unroll
      for (int k = 0; k < 6; k++) sv[k] = acc[k][r] + cst[42 + k];
      float v[6]; float mx = -1e30f;
      #pragma unroll
      for (int i2 = 0; i2 < 6; i2++){
        float a = cst[36 + i2];
        #pragma unroll
        for (int j2 = 0; j2 < 6; j2++) a += cst[i2*6 + j2] * sv[j2];
        v[i2] = a; mx = fmaxf(mx, a);
      }
      float lse = 0.f;
      #pragma unroll
      for (int i2 = 0; i2 < 6; i2++) lse += __expf(v[i2] - mx);
      lse = mx + __logf(lse);
      size_t po = obase + (size_t)(m*48 + n)*6;
      #pragma unroll
      for (int i2 = 0; i2 < 6; i2++) out[po + i2] = v[i2] - lse;
      float sf[5];
      #pragma unroll
      for (int k = 0; k < 5; k++) sf[k] = acc[6 + k][r] + cst[78 + k];
      size_t pf = fbase + (size_t)(m*48 + n)*5;
      #pragma unroll
      for (int i2 = 0; i2 < 5; i2++){
        float a = cst[73 + i2];
        #pragma unroll
        for (int j2 = 0; j2 < 5; j2++) a += cst[48 + i2*5 + j2] * sf[j2];
        out[pf + i2] = a;
      }
    }
  } else {
    size_t abase = 7077888ull + (size_t)b * 4416;
    #pragma unroll
    for (int oc = 0; oc < 6; oc++){
      short8v bv0 = *(const short8v*)&Waf[(size_t)((oc*2 + 0)*64 + L)*8];
      short8v bv1 = *(const short8v*)&Waf[(size_t)((oc*2 + 1)*64 + L)*8];
      f32x4 a = (f32x4){0.f,0.f,0.f,0.f};
      a = __builtin_amdgcn_mfma_f32_16x16x32_bf16(av0, bv0, a, 0, 0, 0);
      a = __builtin_amdgcn_mfma_f32_16x16x32_bf16(av1, bv1, a, 0, 0, 0);
      int o = oc*16 + (L & 15);
      if (o < 92){
        float bb2 = batom[o];
        #pragma unroll
        for (int r = 0; r < 4; r++){
          int m = mr*16 + (L >> 4)*4 + r;
          out[abase + (size_t)m*92 + o] = a[r] + bb2;
        }
      }
    }
  }
}

extern "C" void kernel_launch(void* const* d_in, const int* in_sizes, int n_in,
                              void* d_out, int out_size, void* d_ws, size_t ws_size,
                              hipStream_t stream) {
  const float* atom_fea = (const float*)d_in[0];
  const float* nbr_fea  = (const float*)d_in[1];
  const int*   nbr_idx  = (const int*)d_in[2];
  const int*   cidx     = (const int*)d_in[3];
  const float* W_emb    = (const float*)d_in[4];
  const float* W_full   = (const float*)d_in[5];
  const float* b_full   = (const float*)d_in[6];
  const float* g1       = (const float*)d_in[7];
  const float* be1      = (const float*)d_in[8];
  const float* g2       = (const float*)d_in[9];
  const float* be2      = (const float*)d_in[10];
  const float* W_adj    = (const float*)d_in[11];
  const float* b_adj    = (const float*)d_in[12];
  const float* W_fc1    = (const float*)d_in[13];
  const float* b_fc1    = (const float*)d_in[14];
  const float* W_edge   = (const float*)d_in[15];
  const float* b_edge   = (const float*)d_in[16];
  const float* W_fc2    = (const float*)d_in[17];
  const float* b_fc2    = (const float*)d_in[18];
  const float* W_atom   = (const float*)d_in[19];
  const float* b_atom   = (const float*)d_in[20];

  char* ws = (char*)d_ws;
  float* feaA   = (float*)(ws);                  // 6,291,456
  float* feaB   = (float*)(ws + 6291456);        // 6,291,456
  float* P      = (float*)(ws + 12582912);       // 25,165,824
  float* p2     = (float*)(ws + 12582912);       // aliases P head (P dead during pool/fin2)
  float* p2q    = (float*)(ws + 12779520);       // aliases P
  float* summed = (float*)(ws + 37748736);       // 6,291,456
  float* p1     = (float*)(ws + 44040192);       // 524,288 (1024 x 128)
  float* p1q    = (float*)(ws + 44564480);       // 524,288
  float* sc1    = (float*)(ws + 45088768);       // 512
  float* sh1    = (float*)(ws + 45089280);       // 512
  float* sc2    = (float*)(ws + 45089792);       // 256
  float* sh2    = (float*)(ws + 45090048);       // 256
  bf16*  prep   = (bf16*) (ws + 45090304);       // 249,856
  bf16*  gated  = (bf16*) (ws + 45340160);       // 75,497,472 (end 120,837,632)
  bf16*  Zfrag  = gated;                         // reuses gated (dead by decode)
  float* out    = (float*)d_out;

  bf16* prepProj = prep;                // + l*16384
  bf16* prepEdge = prep + 73728;
  bf16* prepAtom = prep + 118784;

  k_prep_w<<<61, 256, 0, stream>>>(W_full, W_adj, W_edge, W_atom, prep);
  k_embed<<<384, 256, 0, stream>>>(atom_fea, W_emb, feaA);

  // layer 0
  k_proj<<<384, 256, 0, stream>>>(feaA, prepProj, P);
  k_gate<<<1024, 256, 0, stream>>>(P, nbr_fea, nbr_idx, W_full, b_full, gated, p1, p1q);
  k_fin1<<<128, 256, 0, stream>>>(p1, p1q, g1, be1, sc1, sh1);
  k_pool<<<768, 256, 0, stream>>>(gated, sc1, sh1, summed, p2, p2q);
  k_fin2<<<64, 256, 0, stream>>>(p2, p2q, g2, be2, sc2, sh2);

  // layer 1 (update_0 fused into proju)
  k_proju<<<384, 256, 0, stream>>>(feaA, summed, sc2, sh2, feaB, prepProj + 16384, P);
  k_gate<<<1024, 256, 0, stream>>>(P, nbr_fea, nbr_idx, W_full + 21632, b_full + 128, gated, p1, p1q);
  k_fin1<<<128, 256, 0, stream>>>(p1, p1q, g1 + 128, be1 + 128, sc1, sh1);
  k_pool<<<768, 256, 0, stream>>>(gated, sc1, sh1, summed, p2, p2q);
  k_fin2<<<64, 256, 0, stream>>>(p2, p2q, g2 + 64, be2 + 64, sc2, sh2);

  // layer 2 (update_1 fused into proju)
  k_proju<<<384, 256, 0, stream>>>(feaB, summed, sc2, sh2, feaA, prepProj + 32768, P);
  k_gate<<<1024, 256, 0, stream>>>(P, nbr_fea, nbr_idx, W_full + 43264, b_full + 256, gated, p1, p1q);
  k_fin1<<<128, 256, 0, stream>>>(p1, p1q, g1 + 256, be1 + 256, sc1, sh1);
  k_pool<<<768, 256, 0, stream>>>(gated, sc1, sh1, summed, p2, p2q);
  k_fin2<<<64, 256, 0, stream>>>(p2, p2q, g2 + 128, be2 + 128, sc2, sh2);

  // decode (update_2 fused into zfillu; fea3 written to feaB for k_pair)
  k_zfillu<<<512, 256, 0, stream>>>(feaA, summed, sc2, sh2, feaB, cidx, prepEdge, Zfrag);
  k_pair<<<1536, 256, 0, stream>>>(feaB, cidx, Zfrag, prepAtom, b_adj, W_fc1, b_fc1,
                                   b_edge, W_fc2, b_fc2, b_atom, out);
}